// Round 7
// baseline (240.195 us; speedup 1.0000x reference)
//
#include <hip/hip_runtime.h>

// Problem constants (fixed by the reference's setup_inputs)
#define NPEND  128
#define LATENT 256
#define KCOLS  6
#define D0_C   1.0f
#define NB_MAX 1024

typedef float f32x4 __attribute__((ext_vector_type(4)));

// One block per HALF-chain (64 output rows), 128 threads, two phases.
//
// vs round 6 (256-thr full-chain blocks, nt stores, 8 waves/CU): half-size
// blocks + deferred phase-B K loads keep peak VGPR < 128 ->
// __launch_bounds__(128,4) = 16 waves/CU (2x), 8 blocks/CU whose phases
// self-stagger -> read and write streams are mixed machine-wide instead of
// alternating per-CU (copy-kernel regime, 6.3 TB/s m13 ceiling). Stores are
// NORMAL (not nontemporal): the 6.7 TB/s poison fills in this harness use
// normal stores; nt bypass is unproven here and its L3-protection rationale
// is void (fills thrash L3 every iteration anyway).
//
// Geometry: half h of chain c computes r rows rbase..rbase+64 (65 rows,
// rbase = h*64 - h: right halo for h=0, left halo for h=1 -- both in range,
// no clamping) into sR, then emits output rows r0..r0+63 (r0 = h*64).
//
// Phase A: 8 groups of 16 lanes; group g reduces rows rbase+g*8..+7 with a
// statically-indexed 2-deep double buffer (load j covers 256B contiguous
// per 16-lane group). Group 7 additionally does the halo row (i=8).
// Phase B: 4 half-waves; half-wave hw emits rows r0+hw*16..+15 via rolling
// registers (1 broadcast ds_read/row), rank-3 expansion by K^T.
__global__ __launch_bounds__(128, 4)
void pend_fused_kernel(const float* __restrict__ y,
                       const float* __restrict__ K,
                       float* __restrict__ out)
{
    __shared__ float4 sR[65];           // r rows rbase..rbase+64

    const int tid = threadIdx.x;
    const int sl  = tid & 15;           // k-slice lane within group
    const int grp = tid >> 4;           // 0..7
    const int hl  = tid & 31;           // lane within half-wave (phase B)
    const int hw  = tid >> 5;           // 0..3
    const int l0  = hl * 4;

    const int chain = blockIdx.x >> 1;
    const int half  = blockIdx.x & 1;
    const int r0    = half << 6;        // first output row
    const int rbase = r0 - half;        // first r row (65 rows, all in range)

    const float* ybase = y   + (size_t)chain * (NPEND * LATENT);
    float*       obase = out + (size_t)chain * (NPEND * LATENT);

    float4 b0[4], b1[4];                // double buffer, static indices only

    auto issueA = [&](int i, float4 (&b)[4]) {
        const float* p = ybase + (rbase + grp * 8 + i) * LATENT + sl * 4;
        b[0] = *(const float4*)(p);
        b[1] = *(const float4*)(p + 64);
        b[2] = *(const float4*)(p + 128);
        b[3] = *(const float4*)(p + 192);
    };

    // Lead loads first: row i=0 hits HBM while the K gathers issue.
    issueA(0, b0);

    // Phase A K fragment: k(j,e) = j*64 + sl*4 + e (matches load layout).
    float kf0[16], kf1[16], kf2[16];
#pragma unroll
    for (int j = 0; j < 4; ++j)
#pragma unroll
        for (int e = 0; e < 4; ++e) {
            const int k = j * 64 + sl * 4 + e;
            kf0[4 * j + e] = K[k * KCOLS + 0];
            kf1[4 * j + e] = K[k * KCOLS + 1];
            kf2[4 * j + e] = K[k * KCOLS + 2];
        }

    auto consumeA = [&](int i, const float4 (&b)[4]) {
        float s0 = 0.f, s1 = 0.f, s2 = 0.f;
#pragma unroll
        for (int j = 0; j < 4; ++j) {
            const float4 a = b[j];
            s0 += a.x*kf0[4*j] + a.y*kf0[4*j+1] + a.z*kf0[4*j+2] + a.w*kf0[4*j+3];
            s1 += a.x*kf1[4*j] + a.y*kf1[4*j+1] + a.z*kf1[4*j+2] + a.w*kf1[4*j+3];
            s2 += a.x*kf2[4*j] + a.y*kf2[4*j+1] + a.z*kf2[4*j+2] + a.w*kf2[4*j+3];
        }
#pragma unroll
        for (int off = 8; off >= 1; off >>= 1) {
            s0 += __shfl_xor(s0, off, 16);
            s1 += __shfl_xor(s1, off, 16);
            s2 += __shfl_xor(s2, off, 16);
        }
        if (sl == 0) sR[grp * 8 + i] = make_float4(s0, s1, s2, 0.f);
    };

    // ---- Phase A: 2-deep pipeline over 8 rows (+halo row by group 7) ----
    __builtin_amdgcn_sched_barrier(0);
    issueA(1, b1);
    __builtin_amdgcn_sched_barrier(0);
    consumeA(0, b0); issueA(2, b0);
    __builtin_amdgcn_sched_barrier(0);
    consumeA(1, b1); issueA(3, b1);
    __builtin_amdgcn_sched_barrier(0);
    consumeA(2, b0); issueA(4, b0);
    __builtin_amdgcn_sched_barrier(0);
    consumeA(3, b1); issueA(5, b1);
    __builtin_amdgcn_sched_barrier(0);
    consumeA(4, b0); issueA(6, b0);
    __builtin_amdgcn_sched_barrier(0);
    consumeA(5, b1); issueA(7, b1);
    __builtin_amdgcn_sched_barrier(0);
    consumeA(6, b0);
    if (grp == 7) issueA(8, b0);        // halo row rbase+64 (always valid)
    __builtin_amdgcn_sched_barrier(0);
    consumeA(7, b1);
    __builtin_amdgcn_sched_barrier(0);
    if (grp == 7) consumeA(8, b0);

    __syncthreads();   // the only barrier: sR[0..64] complete

    // Phase B K^T fragment loaded HERE (after kf/b0/b1 die) so peak VGPR
    // stays under the 128 cap; K is L2-hot, once per block (~1us total).
    float ka[8], kb[8], kc[8];
#pragma unroll
    for (int e = 0; e < 4; ++e) {
        ka[e]     = K[(l0 + e) * KCOLS + 0];
        kb[e]     = K[(l0 + e) * KCOLS + 1];
        kc[e]     = K[(l0 + e) * KCOLS + 2];
        ka[4 + e] = K[(l0 + 128 + e) * KCOLS + 0];
        kb[4 + e] = K[(l0 + 128 + e) * KCOLS + 1];
        kc[4 + e] = K[(l0 + 128 + e) * KCOLS + 2];
    }

    // ---- Phase B: rolling-register stencil + rank-3 expansion + store ----
    const int li0 = (r0 - rbase) + hw * 16;  // sR index of first output row
    float4 rc = sR[li0];
    float4 rp = (r0 + hw * 16 > 0) ? sR[li0 - 1] : make_float4(0.f, 0.f, 0.f, 0.f);

#pragma unroll
    for (int i = 0; i < 16; ++i) {
        const int row = r0 + hw * 16 + i;
        const int li  = li0 + i;
        const float4 rn = sR[(row < NPEND - 1) ? li + 1 : li];  // clamp

        const float dx = rc.x - rp.x, dy = rc.y - rp.y, dz = rc.z - rp.z;
        const float n  = sqrtf(dx*dx + dy*dy + dz*dz);
        const float s  = (n - D0_C) / n;
        float ox = s * dx, oy = s * dy, oz = s * dz;

        if (row < NPEND - 1) {
            const float ex = rn.x - rc.x, ey = rn.y - rc.y, ez = rn.z - rc.z;
            const float n2 = sqrtf(ex*ex + ey*ey + ez*ez);
            const float t2 = (n2 - D0_C) / n2;
            ox -= t2 * ex; oy -= t2 * ey; oz -= t2 * ez;
        }

        float4 wa, wb;
        wa.x = ox*ka[0] + oy*kb[0] + oz*kc[0];
        wa.y = ox*ka[1] + oy*kb[1] + oz*kc[1];
        wa.z = ox*ka[2] + oy*kb[2] + oz*kc[2];
        wa.w = ox*ka[3] + oy*kb[3] + oz*kc[3];
        wb.x = ox*ka[4] + oy*kb[4] + oz*kc[4];
        wb.y = ox*ka[5] + oy*kb[5] + oz*kc[5];
        wb.z = ox*ka[6] + oy*kb[6] + oz*kc[6];
        wb.w = ox*ka[7] + oy*kb[7] + oz*kc[7];

        float* orow = obase + (size_t)row * LATENT;
        *(float4*)(orow + l0)       = wa;   // normal stores (match fill regime)
        *(float4*)(orow + 128 + l0) = wb;

        rp = rc; rc = rn;
    }
}

extern "C" void kernel_launch(void* const* d_in, const int* in_sizes, int n_in,
                              void* d_out, int out_size, void* d_ws, size_t ws_size,
                              hipStream_t stream) {
    // setup_inputs order: y[f32 N*256], z[f32 N] (unused), K[f32 256*6],
    // batch[int32 N] (unused — shape only).
    const float* y = (const float*)d_in[0];
    const float* K = (const float*)d_in[2];
    float* out = (float*)d_out;

    int N  = (n_in > 1 && in_sizes) ? in_sizes[1] : (1024 * NPEND);
    int nb = N / NPEND;
    if (nb <= 0) nb = 1024;
    if (nb > NB_MAX) nb = NB_MAX;
    (void)out_size; (void)d_ws; (void)ws_size;

    pend_fused_kernel<<<nb * 2, 128, 0, stream>>>(y, K, out);
}

// Round 8
// 236.430 us; speedup vs baseline: 1.0159x; 1.0159x over previous
//
#include <hip/hip_runtime.h>

// Problem constants (fixed by the reference's setup_inputs)
#define NPEND  128
#define LATENT 256
#define KCOLS  6
#define D0_C   1.0f
#define NB_MAX 1024

typedef float f32x4 __attribute__((ext_vector_type(4)));

// One block per CHAIN, 256 threads, two phases (round-6 geometry, best so
// far) + two changes:
//
//  1. K LDS-staged once per block (3 conflict-free scalar loads/thread,
//     round-2 scheme: thread t owns latent t, writes sK[c][t], bank=t%32).
//     Lane K-fragments come from broadcast ds_read_b128 (12 for phase A,
//     6 for phase B) instead of 72 scalar global loads/lane at stride 24B
//     (~24 cache lines per wave-instr ~ 1700 L1 transactions per wave --
//     present in every kernel since round 4; the one mechanism never
//     removed from the critical path).
//  2. Phase-A pipeline deepened 2->3 (b0/b1/b2, statically indexed):
//     per-step stall ~(L-2C) instead of ~(L-C).
//
// Phase A: 16 groups of 16 lanes; group g reduces rows g*8..g*8+7. Load j
// of a row covers y[row][j*64+sl*4..+3] (256B contiguous per group-instr).
// Phase B: 8 half-waves; half-wave hw emits rows hw*16..+15 via rolling
// registers (1 broadcast ds_read/row), rank-3 expansion, nt stores
// (nt > normal: round 6 vs round 7 A/B).
__global__ __launch_bounds__(256, 2)
void pend_fused_kernel(const float* __restrict__ y,
                       const float* __restrict__ K,
                       float* __restrict__ out)
{
    __shared__ float  sK[3][LATENT];    // K^T cols 0..2 (3KB)
    __shared__ float4 sR[NPEND];        // r for the whole chain (2KB)

    const int tid = threadIdx.x;
    const int sl  = tid & 15;           // k-slice lane within group
    const int grp = tid >> 4;           // 0..15: rows grp*8 .. grp*8+7
    const int hl  = tid & 31;           // lane within half-wave (phase B)
    const int hw  = tid >> 5;           // 0..7: rows hw*16 .. hw*16+15
    const int l0  = hl * 4;

    const int chain = blockIdx.x;
    const float* ybase = y   + (size_t)chain * (NPEND * LATENT);
    float*       obase = out + (size_t)chain * (NPEND * LATENT);

    // ---- Stage K (6KB, L2-hot) into LDS: conflict-free, once per block ----
    {
        const float ka = K[tid * KCOLS + 0];
        const float kb = K[tid * KCOLS + 1];
        const float kc = K[tid * KCOLS + 2];
        sK[0][tid] = ka;
        sK[1][tid] = kb;
        sK[2][tid] = kc;
    }
    __syncthreads();

    float4 b0[4], b1[4], b2[4];         // triple buffer, static indices only

    auto issueA = [&](int i, float4 (&b)[4]) {
        const float* p = ybase + (grp * 8 + i) * LATENT + sl * 4;
        b[0] = *(const float4*)(p);
        b[1] = *(const float4*)(p + 64);
        b[2] = *(const float4*)(p + 128);
        b[3] = *(const float4*)(p + 192);
    };

    // Lead loads for 3 pipeline stages, then K fragments from LDS
    // (broadcast ds_read_b128: all 4 groups of a wave read the same addr).
    issueA(0, b0);
    issueA(1, b1);
    issueA(2, b2);

    float4 kf0[4], kf1[4], kf2[4];      // kf*[j] = K[j*64+sl*4 ..+3][c]
#pragma unroll
    for (int j = 0; j < 4; ++j) {
        kf0[j] = *(const float4*)&sK[0][j * 64 + sl * 4];
        kf1[j] = *(const float4*)&sK[1][j * 64 + sl * 4];
        kf2[j] = *(const float4*)&sK[2][j * 64 + sl * 4];
    }

    auto consumeA = [&](int i, const float4 (&b)[4]) {
        float s0 = 0.f, s1 = 0.f, s2 = 0.f;
#pragma unroll
        for (int j = 0; j < 4; ++j) {
            const float4 a = b[j];
            s0 += a.x*kf0[j].x + a.y*kf0[j].y + a.z*kf0[j].z + a.w*kf0[j].w;
            s1 += a.x*kf1[j].x + a.y*kf1[j].y + a.z*kf1[j].z + a.w*kf1[j].w;
            s2 += a.x*kf2[j].x + a.y*kf2[j].y + a.z*kf2[j].z + a.w*kf2[j].w;
        }
#pragma unroll
        for (int off = 8; off >= 1; off >>= 1) {
            s0 += __shfl_xor(s0, off, 16);
            s1 += __shfl_xor(s1, off, 16);
            s2 += __shfl_xor(s2, off, 16);
        }
        if (sl == 0) sR[grp * 8 + i] = make_float4(s0, s1, s2, 0.f);
    };

    // ---- Phase A: 3-deep pipeline over 8 rows ----
    __builtin_amdgcn_sched_barrier(0);
    consumeA(0, b0); issueA(3, b0);
    __builtin_amdgcn_sched_barrier(0);
    consumeA(1, b1); issueA(4, b1);
    __builtin_amdgcn_sched_barrier(0);
    consumeA(2, b2); issueA(5, b2);
    __builtin_amdgcn_sched_barrier(0);
    consumeA(3, b0); issueA(6, b0);
    __builtin_amdgcn_sched_barrier(0);
    consumeA(4, b1); issueA(7, b1);
    __builtin_amdgcn_sched_barrier(0);
    consumeA(5, b2);
    consumeA(6, b0);
    consumeA(7, b1);

    __syncthreads();   // sR complete

    // Phase B K^T fragments from LDS (6 ds_read_b128, after kf/buffers die).
    const float4 kaA = *(const float4*)&sK[0][l0];
    const float4 kaB = *(const float4*)&sK[0][l0 + 128];
    const float4 kbA = *(const float4*)&sK[1][l0];
    const float4 kbB = *(const float4*)&sK[1][l0 + 128];
    const float4 kcA = *(const float4*)&sK[2][l0];
    const float4 kcB = *(const float4*)&sK[2][l0 + 128];

    // ---- Phase B: rolling-register stencil + rank-3 expansion + nt store ----
    const int r0 = hw * 16;
    float4 rc = sR[r0];
    float4 rp = (r0 > 0) ? sR[r0 - 1] : make_float4(0.f, 0.f, 0.f, 0.f);

#pragma unroll
    for (int i = 0; i < 16; ++i) {
        const int row = r0 + i;
        const float4 rn = sR[(row < NPEND - 1) ? row + 1 : row];  // clamp

        const float dx = rc.x - rp.x, dy = rc.y - rp.y, dz = rc.z - rp.z;
        const float n  = sqrtf(dx*dx + dy*dy + dz*dz);
        const float s  = (n - D0_C) / n;
        float ox = s * dx, oy = s * dy, oz = s * dz;

        if (row < NPEND - 1) {
            const float ex = rn.x - rc.x, ey = rn.y - rc.y, ez = rn.z - rc.z;
            const float n2 = sqrtf(ex*ex + ey*ey + ez*ez);
            const float t2 = (n2 - D0_C) / n2;
            ox -= t2 * ex; oy -= t2 * ey; oz -= t2 * ez;
        }

        f32x4 wa, wb;
        wa.x = ox*kaA.x + oy*kbA.x + oz*kcA.x;
        wa.y = ox*kaA.y + oy*kbA.y + oz*kcA.y;
        wa.z = ox*kaA.z + oy*kbA.z + oz*kcA.z;
        wa.w = ox*kaA.w + oy*kbA.w + oz*kcA.w;
        wb.x = ox*kaB.x + oy*kbB.x + oz*kcB.x;
        wb.y = ox*kaB.y + oy*kbB.y + oz*kcB.y;
        wb.z = ox*kaB.z + oy*kbB.z + oz*kcB.z;
        wb.w = ox*kaB.w + oy*kbB.w + oz*kcB.w;

        float* orow = obase + (size_t)row * LATENT;
        __builtin_nontemporal_store(wa, (f32x4*)(orow + l0));
        __builtin_nontemporal_store(wb, (f32x4*)(orow + 128 + l0));

        rp = rc; rc = rn;
    }
}

extern "C" void kernel_launch(void* const* d_in, const int* in_sizes, int n_in,
                              void* d_out, int out_size, void* d_ws, size_t ws_size,
                              hipStream_t stream) {
    // setup_inputs order: y[f32 N*256], z[f32 N] (unused), K[f32 256*6],
    // batch[int32 N] (unused — shape only).
    const float* y = (const float*)d_in[0];
    const float* K = (const float*)d_in[2];
    float* out = (float*)d_out;

    int N  = (n_in > 1 && in_sizes) ? in_sizes[1] : (1024 * NPEND);
    int nb = N / NPEND;
    if (nb <= 0) nb = 1024;
    if (nb > NB_MAX) nb = NB_MAX;
    (void)out_size; (void)d_ws; (void)ws_size;

    pend_fused_kernel<<<nb, 256, 0, stream>>>(y, K, out);
}